// Round 6
// baseline (159.060 us; speedup 1.0000x reference)
//
#include <hip/hip_runtime.h>

// OhemCELoss on MI355X (gfx950).
// pred [B=16, C=5, H=768, W=768] f32; gt [B,H,W] int32; ratio scalar int.
// R5 -> R6: cooperative launch failed to launch at all (harness). Same fusion
// via a plain launch + poison-tolerant flag handshake: 768 blocks stream CE
// and write 16B slots, RELEASE-store a MAGIC flag (agent scope, cross-XCD
// safe); block 0 ACQUIRE-spins on all flags, reduces, writes the scalar.
// Poison-safe: 0xAA..AA != MAGIC; replays rewrite identical slot values, so
// stale/concurrent reads are still bit-correct -> deterministic output.

static constexpr int B_ = 16, C_ = 5, H_ = 768, W_ = 768;
static constexpr int HW_ = H_ * W_;              // 589824
static constexpr int NPIX_ = B_ * HW_;           // 9,437,184
static constexpr int NBLK_ = 768;                // 3 blocks/CU co-residable
static constexpr int BLKS_PER_B_ = NBLK_ / B_;   // 48 blocks per image
static constexpr int PIX_PER_BLK_ = HW_ / BLKS_PER_B_;  // 12288 px
static constexpr int GROUPS_ = 3;                // 3 x (256 thr x 16 px)
static constexpr unsigned MAGIC_ = 0x5ca1ab1eu;

struct Slot { float lp; float lall; unsigned cp; unsigned flag; };  // 16 B

__device__ __forceinline__ unsigned f2ord(float f) {
    unsigned u = __float_as_uint(f);
    return (u & 0x80000000u) ? ~u : (u | 0x80000000u);
}
__device__ __forceinline__ float ord2f(unsigned o) {
    unsigned v = (o & 0x80000000u) ? (o & 0x7FFFFFFFu) : ~o;
    return __uint_as_float(v);
}

// Precise CE (max-subtracted, libm) — used only by the never-taken fallback.
__device__ __forceinline__ float pixel_ce_precise(const float* __restrict__ pred, int p, int t) {
    const int b = p / HW_;
    const int hw = p - b * HW_;
    const float* base = pred + (size_t)b * (C_ * HW_) + hw;
    const float x0 = base[0], x1 = base[HW_], x2 = base[2 * HW_],
                x3 = base[3 * HW_], x4 = base[4 * HW_];
    const float m = fmaxf(fmaxf(fmaxf(x0, x1), fmaxf(x2, x3)), x4);
    const float lse = m + logf(expf(x0 - m) + expf(x1 - m) + expf(x2 - m) +
                               expf(x3 - m) + expf(x4 - m));
    const float xt = (t == 0) ? x0 : (t == 1) ? x1 : (t == 2) ? x2 : (t == 3) ? x3 : x4;
    return lse - xt;
}

__global__ __launch_bounds__(256, 4) void k_fused(const float* __restrict__ pred,
                                                  const int* __restrict__ gt,
                                                  const int* __restrict__ ratio,
                                                  Slot* __restrict__ slots,
                                                  float* __restrict__ out) {
    // ---------------- streaming CE pass (all 768 blocks) ----------------
    const int bb = blockIdx.x / BLKS_PER_B_;                       // uniform per block
    const int hwB = (blockIdx.x - bb * BLKS_PER_B_) * PIX_PER_BLK_;
    const float* base = pred + (size_t)bb * (C_ * HW_) + hwB + threadIdx.x * 4;
    const int* gbase = gt + bb * HW_ + hwB + threadIdx.x * 4;

    float lp = 0.f, lall = 0.f;
    unsigned cp = 0u;

#pragma unroll
    for (int g = 0; g < GROUPS_; ++g) {
        const int off = g * 4096;
        // 16 px/thread: 4 lane-contiguous chunks, 24 independent loads up-front.
        float4 v[4][5];
        int4 t4[4];
#pragma unroll
        for (int c = 0; c < 4; ++c) {
            const float* cb = base + off + c * 1024;
#pragma unroll
            for (int pl = 0; pl < 5; ++pl)
                v[c][pl] = *reinterpret_cast<const float4*>(cb + pl * HW_);
            t4[c] = *reinterpret_cast<const int4*>(gbase + off + c * 1024);
        }
        auto pix = [&](float x0, float x1, float x2, float x3, float x4, int t) {
            const float se = __expf(x0) + __expf(x1) + __expf(x2) + __expf(x3) + __expf(x4);
            const float xt = (t == 0) ? x0 : (t == 1) ? x1 : (t == 2) ? x2
                           : (t == 3) ? x3 : x4;
            const float ce = __logf(se) - xt;
            const bool pos = ((unsigned)(t - 1) <= 2u);
            lall += ce;
            lp += pos ? ce : 0.0f;
            cp += pos ? 1u : 0u;
        };
#pragma unroll
        for (int c = 0; c < 4; ++c) {
            pix(v[c][0].x, v[c][1].x, v[c][2].x, v[c][3].x, v[c][4].x, t4[c].x);
            pix(v[c][0].y, v[c][1].y, v[c][2].y, v[c][3].y, v[c][4].y, t4[c].y);
            pix(v[c][0].z, v[c][1].z, v[c][2].z, v[c][3].z, v[c][4].z, t4[c].z);
            pix(v[c][0].w, v[c][1].w, v[c][2].w, v[c][3].w, v[c][4].w, t4[c].w);
        }
    }

    // block reduce
#pragma unroll
    for (int off = 32; off > 0; off >>= 1) {
        lp += __shfl_down(lp, off);
        lall += __shfl_down(lall, off);
        cp += __shfl_down(cp, off);
    }
    __shared__ float s_lp[4], s_la[4];
    __shared__ unsigned s_cp[4];
    {
        const int wid = threadIdx.x >> 6;
        const int lane = threadIdx.x & 63;
        if (lane == 0) { s_lp[wid] = lp; s_la[wid] = lall; s_cp[wid] = cp; }
        __syncthreads();
        if (threadIdx.x == 0) {
            Slot* s = &slots[blockIdx.x];
            s->lp = s_lp[0] + s_lp[1] + s_lp[2] + s_lp[3];
            s->lall = s_la[0] + s_la[1] + s_la[2] + s_la[3];
            s->cp = s_cp[0] + s_cp[1] + s_cp[2] + s_cp[3];
            // RELEASE: slot data visible device-wide before flag flips.
            __hip_atomic_store(&s->flag, MAGIC_, __ATOMIC_RELEASE,
                               __HIP_MEMORY_SCOPE_AGENT);
        }
    }
    if (blockIdx.x != 0) return;

    // ---------------- finalize (block 0 only) ----------------
    double dlp = 0.0, dla = 0.0;
    unsigned c = 0u;
#pragma unroll
    for (int i = 0; i < NBLK_ / 256; ++i) {
        Slot* s = &slots[i * 256 + threadIdx.x];
        // ACQUIRE spin: only block 0 spins -> no scheduling deadlock.
        while (__hip_atomic_load(&s->flag, __ATOMIC_ACQUIRE,
                                 __HIP_MEMORY_SCOPE_AGENT) != MAGIC_) {}
        dlp += (double)s->lp;
        dla += (double)s->lall;
        c += s->cp;
    }
#pragma unroll
    for (int off = 32; off > 0; off >>= 1) {
        dlp += __shfl_down(dlp, off);
        dla += __shfl_down(dla, off);
        c += __shfl_down(c, off);
    }
    __shared__ double sdp[4], sda[4];
    __shared__ unsigned sc[4];
    __shared__ double t_lp, t_la;
    __shared__ unsigned t_cp;
    {
        const int wid = threadIdx.x >> 6;
        const int lane = threadIdx.x & 63;
        if (lane == 0) { sdp[wid] = dlp; sda[wid] = dla; sc[wid] = c; }
        __syncthreads();
        if (threadIdx.x == 0) {
            t_lp = sdp[0] + sdp[1] + sdp[2] + sdp[3];
            t_la = sda[0] + sda[1] + sda[2] + sda[3];
            t_cp = sc[0] + sc[1] + sc[2] + sc[3];
        }
        __syncthreads();
    }
    const double loss_pos = t_lp;
    const double sum_neg = t_la - t_lp;        // sum CE over ALL negatives
    const unsigned cpx = t_cp;
    const unsigned cn = (unsigned)NPIX_ - cpx;

    const float rf = (float)ratio[0];
    long long nneg_ll = (long long)(rf * (float)cpx);  // f32 mul + trunc, as reference
    if (nneg_ll < 0) nneg_ll = 0;
    const unsigned nneg = (unsigned)((nneg_ll < (long long)cn) ? nneg_ll : (long long)cn);
    const double denom = (double)cpx + (double)nneg;

    if (nneg >= cn) {                 // common case for this input distribution
        if (threadIdx.x == 0)
            out[0] = (denom > 0.0) ? (float)((loss_pos + sum_neg) / denom) : 0.0f;
        return;
    }
    if (nneg == 0) {
        if (threadIdx.x == 0)
            out[0] = (denom > 0.0) ? (float)(loss_pos / denom) : 0.0f;
        return;
    }

    // ---- exact top-k fallback: radix select k-th largest CE among negatives ----
    __shared__ unsigned s_hist[256];
    __shared__ unsigned s_prefix, s_k;
    if (threadIdx.x == 0) { s_prefix = 0u; s_k = nneg; }
    __syncthreads();
    for (int round = 0; round < 4; ++round) {
        const int shift = 24 - 8 * round;
        for (int i = threadIdx.x; i < 256; i += blockDim.x) s_hist[i] = 0u;
        __syncthreads();
        const unsigned prefix = s_prefix;
        const unsigned pmask = (round == 0) ? 0u : (0xFFFFFFFFu << (shift + 8));
        for (int p = threadIdx.x; p < NPIX_; p += blockDim.x) {
            const int t = gt[p];
            if ((unsigned)(t - 1) <= 2u) continue;    // positive — skip
            const unsigned key = f2ord(pixel_ce_precise(pred, p, t));
            if ((key & pmask) == prefix)
                atomicAdd(&s_hist[(key >> shift) & 255u], 1u);
        }
        __syncthreads();
        if (threadIdx.x == 0) {
            const unsigned kk = s_k;
            unsigned cum = 0u;
            for (int i = 255; i >= 0; --i) {
                const unsigned h = s_hist[i];
                if (cum + h >= kk) {
                    s_k = kk - cum;
                    s_prefix = prefix | ((unsigned)i << shift);
                    break;
                }
                cum += h;
            }
        }
        __syncthreads();
    }
    const unsigned Tkey = s_prefix;       // exact key of the k-th largest value
    const float Tval = ord2f(Tkey);
    double sgt = 0.0;
    unsigned cgt = 0u;
    for (int p = threadIdx.x; p < NPIX_; p += blockDim.x) {
        const int t = gt[p];
        if ((unsigned)(t - 1) <= 2u) continue;
        const float ce = pixel_ce_precise(pred, p, t);
        if (f2ord(ce) > Tkey) { sgt += (double)ce; ++cgt; }
    }
#pragma unroll
    for (int off = 32; off > 0; off >>= 1) {
        sgt += __shfl_down(sgt, off);
        cgt += __shfl_down(cgt, off);
    }
    __shared__ double s_s[4];
    __shared__ unsigned s_c[4];
    {
        const int wid = threadIdx.x >> 6;
        const int lane = threadIdx.x & 63;
        if (lane == 0) { s_s[wid] = sgt; s_c[wid] = cgt; }
        __syncthreads();
        if (threadIdx.x == 0) {
            double S = 0.0;
            unsigned Cg = 0u;
            for (int w = 0; w < 4; ++w) { S += s_s[w]; Cg += s_c[w]; }
            const double loss_neg = S + (double)(nneg - Cg) * (double)Tval;  // ties at T
            out[0] = (float)((loss_pos + loss_neg) / denom);
        }
    }
}

extern "C" void kernel_launch(void* const* d_in, const int* in_sizes, int n_in,
                              void* d_out, int out_size, void* d_ws, size_t ws_size,
                              hipStream_t stream) {
    const float* pred = (const float*)d_in[0];
    const int* gt = (const int*)d_in[1];
    const int* ratio = (const int*)d_in[2];
    float* out = (float*)d_out;
    Slot* slots = (Slot*)d_ws;

    k_fused<<<NBLK_, 256, 0, stream>>>(pred, gt, ratio, slots, out);
}

// Round 7
// 99.102 us; speedup vs baseline: 1.6050x; 1.6050x over previous
//
#include <hip/hip_runtime.h>

// OhemCELoss on MI355X (gfx950).
// pred [B=16, C=5, H=768, W=768] f32; gt [B,H,W] int32; ratio scalar int.
// R6 -> R7: R6's fused kernel spilled its load staging to scratch
// (WRITE_SIZE 181MB = 924B/thread, VGPR collapsed to 64). Fix: hot body is
// R4's proven no-spill 16px/thread one-shot (2304 blocks), and the finalize
// tail is fenced off in a __noinline__ device function so its register
// pressure cannot contaminate the hot loop's allocation. Fusion kept via the
// poison-tolerant MAGIC-flag handshake (correctness-proven in R6):
// each block release-stores a flag after its 16B slot; block 0 acquire-spins,
// reduces 2304 slots, writes the scalar. Replays rewrite bit-identical slot
// values, so stale/torn flag-races remain correct -> deterministic.

static constexpr int B_ = 16, C_ = 5, H_ = 768, W_ = 768;
static constexpr int HW_ = H_ * W_;            // 589824
static constexpr int NPIX_ = B_ * HW_;         // 9,437,184
static constexpr int PIX_PER_BLK_ = 4096;      // 256 thr x 16 px
static constexpr int NBLK_ = NPIX_ / PIX_PER_BLK_;      // 2304
static constexpr int BLKS_PER_B_ = HW_ / PIX_PER_BLK_;  // 144
static constexpr unsigned MAGIC_ = 0x5ca1ab1eu;

struct Slot { float lp; float lall; unsigned cp; unsigned flag; };  // 16 B

__device__ __forceinline__ unsigned f2ord(float f) {
    unsigned u = __float_as_uint(f);
    return (u & 0x80000000u) ? ~u : (u | 0x80000000u);
}
__device__ __forceinline__ float ord2f(unsigned o) {
    unsigned v = (o & 0x80000000u) ? (o & 0x7FFFFFFFu) : ~o;
    return __uint_as_float(v);
}

// Precise CE (max-subtracted, libm) — used only by the never-taken fallback.
__device__ float pixel_ce_precise(const float* __restrict__ pred, int p, int t) {
    const int b = p / HW_;
    const int hw = p - b * HW_;
    const float* base = pred + (size_t)b * (C_ * HW_) + hw;
    const float x0 = base[0], x1 = base[HW_], x2 = base[2 * HW_],
                x3 = base[3 * HW_], x4 = base[4 * HW_];
    const float m = fmaxf(fmaxf(fmaxf(x0, x1), fmaxf(x2, x3)), x4);
    const float lse = m + logf(expf(x0 - m) + expf(x1 - m) + expf(x2 - m) +
                               expf(x3 - m) + expf(x4 - m));
    const float xt = (t == 0) ? x0 : (t == 1) ? x1 : (t == 2) ? x2 : (t == 3) ? x3 : x4;
    return lse - xt;
}

// Register-pressure firewall: block 0's finalize lives in its own frame.
__device__ __noinline__ void finalize_fn(const float* __restrict__ pred,
                                         const int* __restrict__ gt,
                                         const int* __restrict__ ratio,
                                         Slot* __restrict__ slots,
                                         float* __restrict__ out) {
    double dlp = 0.0, dla = 0.0;
    unsigned c = 0u;
#pragma unroll
    for (int i = 0; i < NBLK_ / 256; ++i) {
        Slot* s = &slots[i * 256 + threadIdx.x];
        // ACQUIRE spin: only block 0 spins -> no scheduling deadlock.
        while (__hip_atomic_load(&s->flag, __ATOMIC_ACQUIRE,
                                 __HIP_MEMORY_SCOPE_AGENT) != MAGIC_) {}
        dlp += (double)s->lp;
        dla += (double)s->lall;
        c += s->cp;
    }
#pragma unroll
    for (int off = 32; off > 0; off >>= 1) {
        dlp += __shfl_down(dlp, off);
        dla += __shfl_down(dla, off);
        c += __shfl_down(c, off);
    }
    __shared__ double sdp[4], sda[4];
    __shared__ unsigned sc[4];
    __shared__ double t_lp, t_la;
    __shared__ unsigned t_cp;
    {
        const int wid = threadIdx.x >> 6;
        const int lane = threadIdx.x & 63;
        if (lane == 0) { sdp[wid] = dlp; sda[wid] = dla; sc[wid] = c; }
        __syncthreads();
        if (threadIdx.x == 0) {
            t_lp = sdp[0] + sdp[1] + sdp[2] + sdp[3];
            t_la = sda[0] + sda[1] + sda[2] + sda[3];
            t_cp = sc[0] + sc[1] + sc[2] + sc[3];
        }
        __syncthreads();
    }
    const double loss_pos = t_lp;
    const double sum_neg = t_la - t_lp;        // sum CE over ALL negatives
    const unsigned cpx = t_cp;
    const unsigned cn = (unsigned)NPIX_ - cpx;

    const float rf = (float)ratio[0];
    long long nneg_ll = (long long)(rf * (float)cpx);  // f32 mul + trunc, as reference
    if (nneg_ll < 0) nneg_ll = 0;
    const unsigned nneg = (unsigned)((nneg_ll < (long long)cn) ? nneg_ll : (long long)cn);
    const double denom = (double)cpx + (double)nneg;

    if (nneg >= cn) {                 // common case for this input distribution
        if (threadIdx.x == 0)
            out[0] = (denom > 0.0) ? (float)((loss_pos + sum_neg) / denom) : 0.0f;
        return;
    }
    if (nneg == 0) {
        if (threadIdx.x == 0)
            out[0] = (denom > 0.0) ? (float)(loss_pos / denom) : 0.0f;
        return;
    }

    // ---- exact top-k fallback: radix select k-th largest CE among negatives ----
    __shared__ unsigned s_hist[256];
    __shared__ unsigned s_prefix, s_k;
    if (threadIdx.x == 0) { s_prefix = 0u; s_k = nneg; }
    __syncthreads();
    for (int round = 0; round < 4; ++round) {
        const int shift = 24 - 8 * round;
        for (int i = threadIdx.x; i < 256; i += 256) s_hist[i] = 0u;
        __syncthreads();
        const unsigned prefix = s_prefix;
        const unsigned pmask = (round == 0) ? 0u : (0xFFFFFFFFu << (shift + 8));
        for (int p = threadIdx.x; p < NPIX_; p += 256) {
            const int t = gt[p];
            if ((unsigned)(t - 1) <= 2u) continue;    // positive — skip
            const unsigned key = f2ord(pixel_ce_precise(pred, p, t));
            if ((key & pmask) == prefix)
                atomicAdd(&s_hist[(key >> shift) & 255u], 1u);
        }
        __syncthreads();
        if (threadIdx.x == 0) {
            const unsigned kk = s_k;
            unsigned cum = 0u;
            for (int i = 255; i >= 0; --i) {
                const unsigned h = s_hist[i];
                if (cum + h >= kk) {
                    s_k = kk - cum;
                    s_prefix = prefix | ((unsigned)i << shift);
                    break;
                }
                cum += h;
            }
        }
        __syncthreads();
    }
    const unsigned Tkey = s_prefix;       // exact key of the k-th largest value
    const float Tval = ord2f(Tkey);
    double sgt = 0.0;
    unsigned cgt = 0u;
    for (int p = threadIdx.x; p < NPIX_; p += 256) {
        const int t = gt[p];
        if ((unsigned)(t - 1) <= 2u) continue;
        const float ce = pixel_ce_precise(pred, p, t);
        if (f2ord(ce) > Tkey) { sgt += (double)ce; ++cgt; }
    }
#pragma unroll
    for (int off = 32; off > 0; off >>= 1) {
        sgt += __shfl_down(sgt, off);
        cgt += __shfl_down(cgt, off);
    }
    __shared__ double s_s[4];
    __shared__ unsigned s_c[4];
    {
        const int wid = threadIdx.x >> 6;
        const int lane = threadIdx.x & 63;
        if (lane == 0) { s_s[wid] = sgt; s_c[wid] = cgt; }
        __syncthreads();
        if (threadIdx.x == 0) {
            double S = 0.0;
            unsigned Cg = 0u;
            for (int w = 0; w < 4; ++w) { S += s_s[w]; Cg += s_c[w]; }
            const double loss_neg = S + (double)(nneg - Cg) * (double)Tval;  // ties at T
            out[0] = (float)((loss_pos + loss_neg) / denom);
        }
    }
}

__global__ __launch_bounds__(256, 4) void k_fused(const float* __restrict__ pred,
                                                  const int* __restrict__ gt,
                                                  const int* __restrict__ ratio,
                                                  Slot* __restrict__ slots,
                                                  float* __restrict__ out) {
    // ---------------- streaming CE pass: R4's proven hot body ----------------
    const int bb = blockIdx.x / BLKS_PER_B_;                      // uniform per block
    const int hw0 = (blockIdx.x - bb * BLKS_PER_B_) * PIX_PER_BLK_ + threadIdx.x * 4;
    const float* base = pred + (size_t)bb * (C_ * HW_) + hw0;
    const int* gbase = gt + bb * HW_ + hw0;

    // 4 chunks of 1024 px, each lane-contiguous; 24 independent loads total.
    float4 v[4][5];
    int4 t4[4];
#pragma unroll
    for (int c = 0; c < 4; ++c) {
        const float* cb = base + c * 1024;
#pragma unroll
        for (int pl = 0; pl < 5; ++pl)
            v[c][pl] = *reinterpret_cast<const float4*>(cb + pl * HW_);
        t4[c] = *reinterpret_cast<const int4*>(gbase + c * 1024);
    }

    float lp = 0.f, lall = 0.f;
    unsigned cp = 0u;

    auto pix = [&](float x0, float x1, float x2, float x3, float x4, int t) {
        const float se = __expf(x0) + __expf(x1) + __expf(x2) + __expf(x3) + __expf(x4);
        const float xt = (t == 0) ? x0 : (t == 1) ? x1 : (t == 2) ? x2 : (t == 3) ? x3 : x4;
        const float ce = __logf(se) - xt;
        const bool pos = ((unsigned)(t - 1) <= 2u);
        lall += ce;
        lp += pos ? ce : 0.0f;
        cp += pos ? 1u : 0u;
    };
#pragma unroll
    for (int c = 0; c < 4; ++c) {
        pix(v[c][0].x, v[c][1].x, v[c][2].x, v[c][3].x, v[c][4].x, t4[c].x);
        pix(v[c][0].y, v[c][1].y, v[c][2].y, v[c][3].y, v[c][4].y, t4[c].y);
        pix(v[c][0].z, v[c][1].z, v[c][2].z, v[c][3].z, v[c][4].z, t4[c].z);
        pix(v[c][0].w, v[c][1].w, v[c][2].w, v[c][3].w, v[c][4].w, t4[c].w);
    }

    // wave64 reduce
#pragma unroll
    for (int off = 32; off > 0; off >>= 1) {
        lp += __shfl_down(lp, off);
        lall += __shfl_down(lall, off);
        cp += __shfl_down(cp, off);
    }
    __shared__ float s_lp[4], s_la[4];
    __shared__ unsigned s_cp[4];
    const int wid = threadIdx.x >> 6;
    const int lane = threadIdx.x & 63;
    if (lane == 0) { s_lp[wid] = lp; s_la[wid] = lall; s_cp[wid] = cp; }
    __syncthreads();
    if (threadIdx.x == 0) {
        Slot* s = &slots[blockIdx.x];
        s->lp = s_lp[0] + s_lp[1] + s_lp[2] + s_lp[3];
        s->lall = s_la[0] + s_la[1] + s_la[2] + s_la[3];
        s->cp = s_cp[0] + s_cp[1] + s_cp[2] + s_cp[3];
        // RELEASE: slot data visible device-wide before flag flips.
        __hip_atomic_store(&s->flag, MAGIC_, __ATOMIC_RELEASE,
                           __HIP_MEMORY_SCOPE_AGENT);
    }

    if (blockIdx.x != 0) return;
    finalize_fn(pred, gt, ratio, slots, out);   // noinline: own register frame
}

extern "C" void kernel_launch(void* const* d_in, const int* in_sizes, int n_in,
                              void* d_out, int out_size, void* d_ws, size_t ws_size,
                              hipStream_t stream) {
    const float* pred = (const float*)d_in[0];
    const int* gt = (const int*)d_in[1];
    const int* ratio = (const int*)d_in[2];
    float* out = (float*)d_out;
    Slot* slots = (Slot*)d_ws;

    k_fused<<<NBLK_, 256, 0, stream>>>(pred, gt, ratio, slots, out);
}

// Round 9
// 40.569 us; speedup vs baseline: 3.9208x; 2.4428x over previous
//
#include <hip/hip_runtime.h>

// OhemCELoss on MI355X (gfx950).
// pred [B=16, C=5, H=768, W=768] f32; gt [B,H,W] int32; ratio scalar int.
// R8 -> R9: same as R7 (R4 two-kernel structure + nontemporal streaming
// loads) but with clang-native ext_vector_type(4) so
// __builtin_nontemporal_load compiles (HIP_vector_type structs rejected).

static constexpr int B_ = 16, C_ = 5, H_ = 768, W_ = 768;
static constexpr int HW_ = H_ * W_;            // 589824
static constexpr int NPIX_ = B_ * HW_;         // 9,437,184
static constexpr int PIX_PER_BLK_ = 4096;      // 256 thr x 16 px
static constexpr int NBLK_ = NPIX_ / PIX_PER_BLK_;      // 2304
static constexpr int BLKS_PER_B_ = HW_ / PIX_PER_BLK_;  // 144

typedef float f32x4 __attribute__((ext_vector_type(4)));
typedef int i32x4 __attribute__((ext_vector_type(4)));

struct Slot { float lp; float lall; unsigned cp; unsigned pad; };  // 16 B

__device__ __forceinline__ unsigned f2ord(float f) {
    unsigned u = __float_as_uint(f);
    return (u & 0x80000000u) ? ~u : (u | 0x80000000u);
}
__device__ __forceinline__ float ord2f(unsigned o) {
    unsigned v = (o & 0x80000000u) ? (o & 0x7FFFFFFFu) : ~o;
    return __uint_as_float(v);
}

// Precise CE (max-subtracted, libm) — used only by the never-taken fallback.
__device__ float pixel_ce_precise(const float* __restrict__ pred, int p, int t) {
    const int b = p / HW_;
    const int hw = p - b * HW_;
    const float* base = pred + (size_t)b * (C_ * HW_) + hw;
    const float x0 = base[0], x1 = base[HW_], x2 = base[2 * HW_],
                x3 = base[3 * HW_], x4 = base[4 * HW_];
    const float m = fmaxf(fmaxf(fmaxf(x0, x1), fmaxf(x2, x3)), x4);
    const float lse = m + logf(expf(x0 - m) + expf(x1 - m) + expf(x2 - m) +
                               expf(x3 - m) + expf(x4 - m));
    const float xt = (t == 0) ? x0 : (t == 1) ? x1 : (t == 2) ? x2 : (t == 3) ? x3 : x4;
    return lse - xt;
}

__global__ __launch_bounds__(256, 4) void k_ce_pass(const float* __restrict__ pred,
                                                    const int* __restrict__ gt,
                                                    Slot* __restrict__ slots) {
    const int bb = blockIdx.x / BLKS_PER_B_;                      // uniform per block
    const int hw0 = (blockIdx.x - bb * BLKS_PER_B_) * PIX_PER_BLK_ + threadIdx.x * 4;
    const float* base = pred + (size_t)bb * (C_ * HW_) + hw0;
    const int* gbase = gt + bb * HW_ + hw0;

    // 4 chunks of 1024 px, lane-contiguous; 24 independent NT loads up-front.
    f32x4 v[4][5];
    i32x4 t4[4];
#pragma unroll
    for (int c = 0; c < 4; ++c) {
        const float* cb = base + c * 1024;
#pragma unroll
        for (int pl = 0; pl < 5; ++pl)
            v[c][pl] = __builtin_nontemporal_load(
                reinterpret_cast<const f32x4*>(cb + pl * HW_));
        t4[c] = __builtin_nontemporal_load(
            reinterpret_cast<const i32x4*>(gbase + c * 1024));
    }

    float lp = 0.f, lall = 0.f;
    unsigned cp = 0u;

    auto pix = [&](float x0, float x1, float x2, float x3, float x4, int t) {
        const float se = __expf(x0) + __expf(x1) + __expf(x2) + __expf(x3) + __expf(x4);
        const float xt = (t == 0) ? x0 : (t == 1) ? x1 : (t == 2) ? x2 : (t == 3) ? x3 : x4;
        const float ce = __logf(se) - xt;
        const bool pos = ((unsigned)(t - 1) <= 2u);
        lall += ce;
        lp += pos ? ce : 0.0f;
        cp += pos ? 1u : 0u;
    };
#pragma unroll
    for (int c = 0; c < 4; ++c) {
#pragma unroll
        for (int j = 0; j < 4; ++j)
            pix(v[c][0][j], v[c][1][j], v[c][2][j], v[c][3][j], v[c][4][j], t4[c][j]);
    }

    // wave64 reduce
#pragma unroll
    for (int off = 32; off > 0; off >>= 1) {
        lp += __shfl_down(lp, off);
        lall += __shfl_down(lall, off);
        cp += __shfl_down(cp, off);
    }
    __shared__ float s_lp[4], s_la[4];
    __shared__ unsigned s_cp[4];
    const int wid = threadIdx.x >> 6;
    const int lane = threadIdx.x & 63;
    if (lane == 0) { s_lp[wid] = lp; s_la[wid] = lall; s_cp[wid] = cp; }
    __syncthreads();
    if (threadIdx.x == 0) {
        Slot s;
        s.lp = s_lp[0] + s_lp[1] + s_lp[2] + s_lp[3];
        s.lall = s_la[0] + s_la[1] + s_la[2] + s_la[3];
        s.cp = s_cp[0] + s_cp[1] + s_cp[2] + s_cp[3];
        s.pad = 0u;
        slots[blockIdx.x] = s;       // private 16B slot — no atomics anywhere
    }
}

__global__ __launch_bounds__(256) void k_finalize(const float* __restrict__ pred,
                                                  const int* __restrict__ gt,
                                                  const int* __restrict__ ratio,
                                                  const Slot* __restrict__ slots,
                                                  float* __restrict__ out) {
    // ---- reduce the 2304 slots (9 independent unrolled loads) ----
    double dlp = 0.0, dla = 0.0;
    unsigned c = 0u;
#pragma unroll
    for (int i = 0; i < NBLK_ / 256; ++i) {
        const Slot s = slots[i * 256 + threadIdx.x];
        dlp += (double)s.lp;
        dla += (double)s.lall;
        c += s.cp;
    }
#pragma unroll
    for (int off = 32; off > 0; off >>= 1) {
        dlp += __shfl_down(dlp, off);
        dla += __shfl_down(dla, off);
        c += __shfl_down(c, off);
    }
    __shared__ double sdp[4], sda[4];
    __shared__ unsigned sc[4];
    __shared__ double t_lp, t_la;
    __shared__ unsigned t_cp;
    {
        const int wid = threadIdx.x >> 6;
        const int lane = threadIdx.x & 63;
        if (lane == 0) { sdp[wid] = dlp; sda[wid] = dla; sc[wid] = c; }
        __syncthreads();
        if (threadIdx.x == 0) {
            t_lp = sdp[0] + sdp[1] + sdp[2] + sdp[3];
            t_la = sda[0] + sda[1] + sda[2] + sda[3];
            t_cp = sc[0] + sc[1] + sc[2] + sc[3];
        }
        __syncthreads();
    }
    const double loss_pos = t_lp;
    const double sum_neg = t_la - t_lp;        // sum CE over ALL negatives
    const unsigned cp = t_cp;
    const unsigned cn = (unsigned)NPIX_ - cp;

    const float rf = (float)ratio[0];
    long long nneg_ll = (long long)(rf * (float)cp);   // f32 mul + trunc, as reference
    if (nneg_ll < 0) nneg_ll = 0;
    const unsigned nneg = (unsigned)((nneg_ll < (long long)cn) ? nneg_ll : (long long)cn);
    const double denom = (double)cp + (double)nneg;

    if (nneg >= cn) {                 // common case for this input distribution
        if (threadIdx.x == 0)
            out[0] = (denom > 0.0) ? (float)((loss_pos + sum_neg) / denom) : 0.0f;
        return;
    }
    if (nneg == 0) {
        if (threadIdx.x == 0)
            out[0] = (denom > 0.0) ? (float)(loss_pos / denom) : 0.0f;
        return;
    }

    // ---- exact top-k fallback: radix select k-th largest CE among negatives ----
    __shared__ unsigned s_hist[256];
    __shared__ unsigned s_prefix, s_k;
    if (threadIdx.x == 0) { s_prefix = 0u; s_k = nneg; }
    __syncthreads();
    for (int round = 0; round < 4; ++round) {
        const int shift = 24 - 8 * round;
        for (int i = threadIdx.x; i < 256; i += blockDim.x) s_hist[i] = 0u;
        __syncthreads();
        const unsigned prefix = s_prefix;
        const unsigned pmask = (round == 0) ? 0u : (0xFFFFFFFFu << (shift + 8));
        for (int p = threadIdx.x; p < NPIX_; p += blockDim.x) {
            const int t = gt[p];
            if ((unsigned)(t - 1) <= 2u) continue;    // positive — skip
            const unsigned key = f2ord(pixel_ce_precise(pred, p, t));
            if ((key & pmask) == prefix)
                atomicAdd(&s_hist[(key >> shift) & 255u], 1u);
        }
        __syncthreads();
        if (threadIdx.x == 0) {
            const unsigned kk = s_k;
            unsigned cum = 0u;
            for (int i = 255; i >= 0; --i) {
                const unsigned h = s_hist[i];
                if (cum + h >= kk) {
                    s_k = kk - cum;
                    s_prefix = prefix | ((unsigned)i << shift);
                    break;
                }
                cum += h;
            }
        }
        __syncthreads();
    }
    const unsigned Tkey = s_prefix;       // exact key of the k-th largest value
    const float Tval = ord2f(Tkey);
    double sgt = 0.0;
    unsigned cgt = 0u;
    for (int p = threadIdx.x; p < NPIX_; p += blockDim.x) {
        const int t = gt[p];
        if ((unsigned)(t - 1) <= 2u) continue;
        const float ce = pixel_ce_precise(pred, p, t);
        if (f2ord(ce) > Tkey) { sgt += (double)ce; ++cgt; }
    }
#pragma unroll
    for (int off = 32; off > 0; off >>= 1) {
        sgt += __shfl_down(sgt, off);
        cgt += __shfl_down(cgt, off);
    }
    __shared__ double s_s[4];
    __shared__ unsigned s_c[4];
    const int wid = threadIdx.x >> 6;
    const int lane = threadIdx.x & 63;
    if (lane == 0) { s_s[wid] = sgt; s_c[wid] = cgt; }
    __syncthreads();
    if (threadIdx.x == 0) {
        double S = 0.0;
        unsigned Cg = 0u;
        for (int w = 0; w < 4; ++w) { S += s_s[w]; Cg += s_c[w]; }
        const double loss_neg = S + (double)(nneg - Cg) * (double)Tval;  // ties at T
        out[0] = (float)((loss_pos + loss_neg) / denom);
    }
}

extern "C" void kernel_launch(void* const* d_in, const int* in_sizes, int n_in,
                              void* d_out, int out_size, void* d_ws, size_t ws_size,
                              hipStream_t stream) {
    const float* pred = (const float*)d_in[0];
    const int* gt = (const int*)d_in[1];
    const int* ratio = (const int*)d_in[2];
    float* out = (float*)d_out;
    Slot* slots = (Slot*)d_ws;

    k_ce_pass<<<NBLK_, 256, 0, stream>>>(pred, gt, slots);   // writes every slot
    k_finalize<<<1, 256, 0, stream>>>(pred, gt, ratio, slots, out);
}